// Round 6
// baseline (249.800 us; speedup 1.0000x reference)
//
#include <hip/hip_runtime.h>

// LeakyIntegrator: T=4096 scan over B=8192 columns, fp32. x is EXACTLY {0,1}.
// Algebraic reduction: with m_t = d*(m_{t-1}+x_t)   (= n10+n11, decayed ones),
//   na1_t = m_{t-1}                       (EXACT identity, same fp op sequence)
//   na0_t = S_t - m_{t-1},  S_t = d*(S_{t-1}+1) = d(1-d^t)/(1-d)   (data-independent)
//   n10_t = m_t - n11_t
// => only TWO data-dependent states (m, n11) + bit-packed x (u64 per 64-row chunk).
// Round 6: 3-kernel structure (fusions failed/regressed in R2/R5). Occupancy push:
// VEC=1, 2048 blocks = 8 blocks/CU = 32 waves/CU (HW max), launch_bounds(256,8)
// caps VGPR at 64. Streaming x loads are nontemporal (read-once). final reads its
// prev-bit from x[t0-1] (4B) instead of the prev-chunk mask (8B).
// ws layout (8 MiB):
//   [0, 2 MiB)  : m   locals [NCHUNK][B_DIM] float
//   [2, 4 MiB)  : n11 locals [NCHUNK][B_DIM] float
//   [4, 8 MiB)  : packed x bits [NCHUNK][B_DIM] u64

constexpr int T_DIM  = 4096;
constexpr int B_DIM  = 8192;
constexpr int NCHUNK = 64;
constexpr int CLEN   = T_DIM / NCHUNK;   // 64
constexpr int UNROLL = 8;                // rows per load batch (2-batch pipeline)
constexpr int BLOCK  = 256;

typedef unsigned long long u64;

__global__ __launch_bounds__(BLOCK, 8) void partial_kernel(
    const float* __restrict__ x, const float* __restrict__ dptr,
    float* __restrict__ ws)
{
    const float d  = *dptr;
    const int   c  = blockIdx.y;
    const int   b0 = blockIdx.x * BLOCK + (int)threadIdx.x;   // column
    const long  t0 = (long)c * CLEN;

    float prev = (c == 0) ? 0.0f
               : __builtin_nontemporal_load(x + (t0 - 1) * B_DIM + b0);

    float m = 0.f, n11 = 0.f;
    u64   mask = 0ull;

    const float* p = x + t0 * B_DIM + b0;

    // two-batch software pipeline: next batch's loads in flight while current
    // batch is consumed. Static indexing only (named A/Bv), full unroll.
    float A[UNROLL], Bv[UNROLL];
    #pragma unroll
    for (int u = 0; u < UNROLL; ++u)
        A[u] = __builtin_nontemporal_load(p + (size_t)u * B_DIM);

    auto compute = [&](const float* buf, int kbase) {
        #pragma unroll
        for (int u = 0; u < UNROLL; ++u) {
            const int   k  = kbase + u;
            const float xt = buf[u];
            mask |= (u64)(unsigned)xt << k;          // xt is exactly 0.0 or 1.0
            m    = d * (m + xt);
            n11  = d * (n11 + xt * prev);
            prev = xt;
        }
    };

    #pragma unroll
    for (int kk = 0; kk < CLEN; kk += 2 * UNROLL) {
        #pragma unroll
        for (int u = 0; u < UNROLL; ++u)
            Bv[u] = __builtin_nontemporal_load(p + (size_t)(kk + UNROLL + u) * B_DIM);
        compute(A, kk);
        if (kk + 2 * UNROLL < CLEN) {               // compile-time after unroll
            #pragma unroll
            for (int u = 0; u < UNROLL; ++u)
                A[u] = __builtin_nontemporal_load(p + (size_t)(kk + 2 * UNROLL + u) * B_DIM);
        }
        compute(Bv, kk + UNROLL);
    }

    // locals + bits are consumed by the NEXT kernels: nontemporal keeps L2 clean.
    float* wm = ws + (size_t)c * B_DIM + b0;
    __builtin_nontemporal_store(m,   wm);
    __builtin_nontemporal_store(n11, wm + (size_t)NCHUNK * B_DIM);

    u64* bits = reinterpret_cast<u64*>(ws + (size_t)2 * NCHUNK * B_DIM);
    __builtin_nontemporal_store(mask, &bits[(size_t)c * B_DIM + b0]);
}

// One thread per (state, column): 2*8192 = 16384 threads, 64-thread blocks so
// all 256 CUs participate. All 64 chunk-local loads hoisted before the fold.
__global__ __launch_bounds__(64) void scan_kernel(
    const float* __restrict__ dptr, float* __restrict__ ws)
{
    float dL = *dptr;                 // d^CLEN, CLEN = 64 = 2^6
    #pragma unroll
    for (int i = 0; i < 6; ++i) dL = dL * dL;

    const int tid = blockIdx.x * 64 + (int)threadIdx.x;   // [0, 2*B)
    float* p = ws + (size_t)(tid >> 13) * NCHUNK * B_DIM + (tid & (B_DIM - 1));

    float l[NCHUNK];
    #pragma unroll
    for (int c = 0; c < NCHUNK; ++c) l[c] = p[(size_t)c * B_DIM];

    float s = 0.f;
    #pragma unroll
    for (int c = 0; c < NCHUNK; ++c) {
        p[(size_t)c * B_DIM] = s;     // incoming state for chunk c
        s = dL * s + l[c];
    }
}

__global__ __launch_bounds__(BLOCK, 8) void final_kernel(
    const float* __restrict__ x, const float* __restrict__ dptr,
    const float* __restrict__ ws, float* __restrict__ out)
{
    const float d = *dptr;
    float dL = d;
    #pragma unroll
    for (int i = 0; i < 6; ++i) dL = dL * dL;                  // d^64

    const int  c  = blockIdx.y;
    const int  b0 = blockIdx.x * BLOCK + (int)threadIdx.x;     // column
    const long t0 = (long)c * CLEN;

    const float* w = ws + (size_t)c * B_DIM + b0;
    float m   = w[0];
    float n11 = w[(size_t)NCHUNK * B_DIM];

    // incoming na_sum = d*(1 - d^(64c)) / (1-d); 1-d is EXACT for d in [0.5,1)
    float dLc = 1.f, sq = dL;
    int cc = c;
    #pragma unroll
    for (int i = 0; i < 6; ++i) { if (cc & 1) dLc *= sq; sq *= sq; cc >>= 1; }
    float na = d * (1.f - dLc) / (1.f - d);

    const u64* bits = reinterpret_cast<const u64*>(ws + (size_t)2 * NCHUNK * B_DIM);
    u64 mask = bits[(size_t)c * B_DIM + b0];

    bool pb = (c == 0) ? false
            : (__builtin_nontemporal_load(x + (t0 - 1) * B_DIM + b0) != 0.0f);

    float* q = out + (size_t)c * CLEN * B_DIM + b0;
    for (int kk = 0; kk < CLEN; kk += UNROLL) {
        #pragma unroll
        for (int u = 0; u < UNROLL; ++u) {
            const int k = kk + u;
            na = d * (na + 1.f);                     // uniform, 1 op per row
            const bool  xb = (mask >> k) & 1ull;
            const float mo = m;                      // = na1_t (exact identity)
            m   = d * (mo + (xb ? 1.f : 0.f));
            n11 = d * (n11 + ((xb && pb) ? 1.f : 0.f));
            const float num = xb ? (n11 + 1.f) : (m - n11 + 1.f);
            const float den = xb ? (mo + 2.f)  : (na - mo + 2.f);
            const float pr  = num * __builtin_amdgcn_rcpf(den);  // ONE rcp/element
            pb = xb;
            __builtin_nontemporal_store(pr, q + (size_t)u * B_DIM);
        }
        q += (size_t)UNROLL * B_DIM;
    }
}

extern "C" void kernel_launch(void* const* d_in, const int* in_sizes, int n_in,
                              void* d_out, int out_size, void* d_ws, size_t ws_size,
                              hipStream_t stream) {
    const float* x  = (const float*)d_in[0];
    const float* dr = (const float*)d_in[1];
    float* ws  = (float*)d_ws;    // needs 8 MiB
    float* out = (float*)d_out;

    dim3 blk(BLOCK);
    dim3 grid1(B_DIM / BLOCK, NCHUNK);   // (32, 64) = 2048 blocks = 8/CU, 32 waves/CU
    partial_kernel<<<grid1, blk, 0, stream>>>(x, dr, ws);
    scan_kernel<<<(2 * B_DIM) / 64, dim3(64), 0, stream>>>(dr, ws);
    final_kernel<<<grid1, blk, 0, stream>>>(x, dr, ws, out);
}

// Round 7
// 237.844 us; speedup vs baseline: 1.0503x; 1.0503x over previous
//
#include <hip/hip_runtime.h>

// LeakyIntegrator: T=4096 scan over B=8192 columns, fp32. x is EXACTLY {0,1}.
// Algebraic reduction: with m_t = d*(m_{t-1}+x_t)   (= n10+n11, decayed ones),
//   na1_t = m_{t-1}                       (EXACT identity, same fp op sequence)
//   na0_t = S_t - m_{t-1},  S_t = d*(S_{t-1}+1) = d(1-d^t)/(1-d)   (data-independent)
//   n10_t = m_t - n11_t
// => only TWO data-dependent states (m, n11) + bit-packed x (u64 per 64-row chunk).
// Round 7 = round 3 (best measured, 236.27) + one polish: final reads its
// prev-bit from x[t0-1] (4 B/thread, L3-resident) instead of the prev chunk's
// u64 masks (16 B/thread) -- bit 63 of chunk c-1's mask == x[64c-1] exactly.
// Geometry ledger (measured): VEC=2/1024blk=236.3 < VEC=4/512blk=239.2 <
// NCHUNK=128/VEC=4=243.2 < VEC=1/nt/2048blk=249.8. Fusions: R2 -43%, R5 fail.
// ws layout (8 MiB):
//   [0, 2 MiB)  : m   locals [NCHUNK][B_DIM] float
//   [2, 4 MiB)  : n11 locals [NCHUNK][B_DIM] float
//   [4, 8 MiB)  : packed x bits [NCHUNK][B_DIM] u64

constexpr int T_DIM  = 4096;
constexpr int B_DIM  = 8192;
constexpr int NCHUNK = 64;
constexpr int CLEN   = T_DIM / NCHUNK;   // 64
constexpr int VEC    = 2;                // columns per thread
constexpr int UNROLL = 8;                // rows per load batch
constexpr int BLOCK  = 256;

typedef float v2f __attribute__((ext_vector_type(2)));
typedef unsigned long long u64;
typedef u64 v2u __attribute__((ext_vector_type(2)));

__global__ __launch_bounds__(BLOCK) void partial_kernel(
    const float* __restrict__ x, const float* __restrict__ dptr,
    float* __restrict__ ws)
{
    const float d  = *dptr;
    const int   c  = blockIdx.y;
    const int   b0 = (blockIdx.x * BLOCK + (int)threadIdx.x) * VEC;
    const long  t0 = (long)c * CLEN;

    float prev[VEC];
    if (c == 0) {
        prev[0] = prev[1] = 0.0f;
    } else {
        const v2f pv = *reinterpret_cast<const v2f*>(x + (t0 - 1) * B_DIM + b0);
        prev[0] = pv[0]; prev[1] = pv[1];
    }

    float m[VEC]   = {0.f, 0.f};
    float n11[VEC] = {0.f, 0.f};
    u64   mask[VEC] = {0ull, 0ull};

    const float* p = x + t0 * B_DIM + b0;

    // two-batch software pipeline: next batch's loads in flight while current
    // batch is consumed. Static indexing only (named A/Bv), full unroll.
    v2f A[UNROLL], Bv[UNROLL];
    #pragma unroll
    for (int u = 0; u < UNROLL; ++u)
        A[u] = *reinterpret_cast<const v2f*>(p + (size_t)u * B_DIM);

    auto compute = [&](const v2f* buf, int kbase) {
        #pragma unroll
        for (int u = 0; u < UNROLL; ++u) {
            const int k = kbase + u;
            #pragma unroll
            for (int j = 0; j < VEC; ++j) {
                const float xt = buf[u][j];
                mask[j] |= (u64)(unsigned)xt << k;   // xt is exactly 0.0 or 1.0
                m[j]   = d * (m[j] + xt);
                n11[j] = d * (n11[j] + xt * prev[j]);
                prev[j] = xt;
            }
        }
    };

    #pragma unroll
    for (int kk = 0; kk < CLEN; kk += 2 * UNROLL) {
        #pragma unroll
        for (int u = 0; u < UNROLL; ++u)
            Bv[u] = *reinterpret_cast<const v2f*>(p + (size_t)(kk + UNROLL + u) * B_DIM);
        compute(A, kk);
        if (kk + 2 * UNROLL < CLEN) {               // compile-time after unroll
            #pragma unroll
            for (int u = 0; u < UNROLL; ++u)
                A[u] = *reinterpret_cast<const v2f*>(p + (size_t)(kk + 2 * UNROLL + u) * B_DIM);
        }
        compute(Bv, kk + UNROLL);
    }

    // locals + bits are consumed by the NEXT kernels (cross-XCD, via L3):
    // nontemporal stores keep L2 clean during the streaming read phase.
    float* wm = ws + (size_t)c * B_DIM + b0;
    v2f mv, nv;
    mv[0] = m[0];   mv[1] = m[1];
    nv[0] = n11[0]; nv[1] = n11[1];
    __builtin_nontemporal_store(mv, reinterpret_cast<v2f*>(wm));
    __builtin_nontemporal_store(nv, reinterpret_cast<v2f*>(wm + (size_t)NCHUNK * B_DIM));

    u64* bits = reinterpret_cast<u64*>(ws + (size_t)2 * NCHUNK * B_DIM);
    v2u bm; bm[0] = mask[0]; bm[1] = mask[1];
    __builtin_nontemporal_store(bm, reinterpret_cast<v2u*>(&bits[(size_t)c * B_DIM + b0]));
}

// One thread per (state, column): 2*8192 = 16384 threads, 64-thread blocks so
// all 256 CUs participate. All 64 chunk-local loads hoisted before the fold.
__global__ __launch_bounds__(64) void scan_kernel(
    const float* __restrict__ dptr, float* __restrict__ ws)
{
    float dL = *dptr;                 // d^CLEN, CLEN = 64 = 2^6
    #pragma unroll
    for (int i = 0; i < 6; ++i) dL = dL * dL;

    const int tid = blockIdx.x * 64 + (int)threadIdx.x;   // [0, 2*B)
    float* p = ws + (size_t)(tid >> 13) * NCHUNK * B_DIM + (tid & (B_DIM - 1));

    float l[NCHUNK];
    #pragma unroll
    for (int c = 0; c < NCHUNK; ++c) l[c] = p[(size_t)c * B_DIM];

    float s = 0.f;
    #pragma unroll
    for (int c = 0; c < NCHUNK; ++c) {
        p[(size_t)c * B_DIM] = s;     // incoming state for chunk c
        s = dL * s + l[c];
    }
}

__global__ __launch_bounds__(BLOCK) void final_kernel(
    const float* __restrict__ x, const float* __restrict__ dptr,
    const float* __restrict__ ws, float* __restrict__ out)
{
    const float d = *dptr;
    float dL = d;
    #pragma unroll
    for (int i = 0; i < 6; ++i) dL = dL * dL;                  // d^64

    const int  c  = blockIdx.y;
    const int  b0 = (blockIdx.x * BLOCK + (int)threadIdx.x) * VEC;
    const long t0 = (long)c * CLEN;

    const float* w = ws + (size_t)c * B_DIM + b0;
    const v2f mi = *reinterpret_cast<const v2f*>(w);
    const v2f ni = *reinterpret_cast<const v2f*>(w + (size_t)NCHUNK * B_DIM);
    float m[VEC]   = {mi[0], mi[1]};
    float n11[VEC] = {ni[0], ni[1]};

    // incoming na_sum = d*(1 - d^(64c)) / (1-d); 1-d is EXACT for d in [0.5,1)
    float dLc = 1.f, sq = dL;
    int cc = c;
    #pragma unroll
    for (int i = 0; i < 6; ++i) { if (cc & 1) dLc *= sq; sq *= sq; cc >>= 1; }
    float na = d * (1.f - dLc) / (1.f - d);

    const u64* bits = reinterpret_cast<const u64*>(ws + (size_t)2 * NCHUNK * B_DIM);
    const v2u bm = *reinterpret_cast<const v2u*>(&bits[(size_t)c * B_DIM + b0]);
    u64 mask[VEC] = {bm[0], bm[1]};

    // prev-bit from x[t0-1] (4 B/thread, L3-resident) instead of prev-chunk
    // masks (16 B/thread): bit 63 of chunk c-1's mask == x[64c-1] exactly.
    bool pb[VEC];
    if (c == 0) {
        pb[0] = pb[1] = false;
    } else {
        const v2f pv = *reinterpret_cast<const v2f*>(x + (t0 - 1) * B_DIM + b0);
        pb[0] = (pv[0] != 0.0f);
        pb[1] = (pv[1] != 0.0f);
    }

    float* q = out + (size_t)c * CLEN * B_DIM + b0;
    for (int kk = 0; kk < CLEN; kk += UNROLL) {
        #pragma unroll
        for (int u = 0; u < UNROLL; ++u) {
            const int k = kk + u;
            na = d * (na + 1.f);                     // uniform, 1 op per row
            float pr[VEC];
            #pragma unroll
            for (int j = 0; j < VEC; ++j) {
                const bool  xb = (mask[j] >> k) & 1ull;
                const float mo = m[j];               // = na1_t (exact identity)
                m[j]   = d * (mo + (xb ? 1.f : 0.f));
                n11[j] = d * (n11[j] + ((xb && pb[j]) ? 1.f : 0.f));
                const float num = xb ? (n11[j] + 1.f) : (m[j] - n11[j] + 1.f);
                const float den = xb ? (mo + 2.f)     : (na - mo + 2.f);
                pr[j] = num * __builtin_amdgcn_rcpf(den);   // ONE rcp per element
                pb[j] = xb;
            }
            v2f ov; ov[0] = pr[0]; ov[1] = pr[1];
            __builtin_nontemporal_store(ov, reinterpret_cast<v2f*>(q + (size_t)u * B_DIM));
        }
        q += (size_t)UNROLL * B_DIM;
    }
}

extern "C" void kernel_launch(void* const* d_in, const int* in_sizes, int n_in,
                              void* d_out, int out_size, void* d_ws, size_t ws_size,
                              hipStream_t stream) {
    const float* x  = (const float*)d_in[0];
    const float* dr = (const float*)d_in[1];
    float* ws  = (float*)d_ws;    // needs 8 MiB
    float* out = (float*)d_out;

    dim3 blk(BLOCK);
    dim3 grid1(B_DIM / VEC / BLOCK, NCHUNK);   // (16, 64) = 1024 blocks
    partial_kernel<<<grid1, blk, 0, stream>>>(x, dr, ws);
    scan_kernel<<<(2 * B_DIM) / 64, dim3(64), 0, stream>>>(dr, ws);
    final_kernel<<<grid1, blk, 0, stream>>>(x, dr, ws, out);
}